// Round 1
// baseline (317.551 us; speedup 1.0000x reference)
//
#include <hip/hip_runtime.h>
#include <math.h>

#define TB 2
#define TT 2048
#define NHEADS 16
#define HDIM 64
#define HSZ 1024
#define KT 32
#define QW 16
#define NWAVES 4
#define QB 64

typedef float floatx4 __attribute__((ext_vector_type(4)));
typedef __bf16 bf16x8 __attribute__((ext_vector_type(8)));

__global__ __launch_bounds__(256)
void attn_rope_alibi_kernel(const float* __restrict__ Q,
                            const float* __restrict__ K,
                            const float* __restrict__ V,
                            float* __restrict__ Out)
{
    const int blk   = blockIdx.x;
    const int qtile = blk & 31;          // T/QB = 32
    const int h     = (blk >> 5) & 15;
    const int b     = blk >> 9;

    const int tid    = threadIdx.x;
    const int wave   = tid >> 6;
    const int lane   = tid & 63;
    const int lane15 = lane & 15;
    const int quad   = lane >> 4;

    // K tile row stride 72 bf16 = 144 B (16B multiple, 2-way banks on b128)
    // V^T row stride 40 bf16 = 80 B (16B multiple, 2-way banks)
    // P  row stride 40 bf16
    __shared__ __align__(16) __bf16 sK[KT][72];
    __shared__ __align__(16) __bf16 sV[HDIM][40];
    __shared__ __align__(16) __bf16 sP[NWAVES][QW][40];

    const float scale  = 0.125f;                      // 1/sqrt(64)
    const float slope  = exp2f(-0.5f * (float)(h + 1)); // 2^(-8(h+1)/16)
    const float NEGF   = -13.287712379549449f / 32.0f; // -(log2 10000)/32
    const float INV2PI = 0.15915494309189535f;

    // ---- load & RoPE Q into A-fragments (A[m=lane15][k=quad*8+j]) ----
    const int t_q = qtile * QB + wave * QW + lane15;
    const int d0  = quad * 8;                         // 0,8,16,24  (first half)
    const float* qrow = Q + (((size_t)b * TT + t_q) * HSZ) + h * HDIM;
    float q0[8], q1[8];
    *(floatx4*)&q0[0] = *(const floatx4*)&qrow[d0];
    *(floatx4*)&q0[4] = *(const floatx4*)&qrow[d0 + 4];
    *(floatx4*)&q1[0] = *(const floatx4*)&qrow[d0 + 32];
    *(floatx4*)&q1[4] = *(const floatx4*)&qrow[d0 + 36];

    bf16x8 aQ0, aQ1;
    #pragma unroll
    for (int j = 0; j < 8; ++j) {
        float freq = exp2f((float)(d0 + j) * NEGF);
        float rv   = (float)t_q * freq * INV2PI;
        rv -= floorf(rv);                              // revolutions in [0,1)
        float s = __builtin_amdgcn_sinf(rv);
        float c = __builtin_amdgcn_cosf(rv);
        aQ0[j] = (__bf16)(q0[j] * c - q1[j] * s);      // d < 32: rot = -x[d+32]
        aQ1[j] = (__bf16)(q1[j] * c + q0[j] * s);      // d >=32: rot = +x[d-32]
    }

    floatx4 O0 = {0.f,0.f,0.f,0.f}, O1 = O0, O2 = O0, O3 = O0;
    float mrow[4] = {-INFINITY, -INFINITY, -INFINITY, -INFINITY};
    float lrow[4] = {0.f, 0.f, 0.f, 0.f};

    const float* kbh = K + ((size_t)b * TT) * HSZ + h * HDIM;
    const float* vbh = V + ((size_t)b * TT) * HSZ + h * HDIM;

    const int q_glb_base = qtile * QB + wave * QW + quad * 4; // C-layout row base

    for (int kt = 0; kt < TT / KT; ++kt) {
        __syncthreads();
        // ---- stage K tile with RoPE: thread -> key=tid/8, dims (tid%8)*4 (+32) ----
        {
            const int key = tid >> 3;
            const int dg  = (tid & 7) * 4;
            const int t_k = kt * KT + key;
            const float* krow = kbh + (size_t)t_k * HSZ;
            floatx4 k0 = *(const floatx4*)&krow[dg];
            floatx4 k1 = *(const floatx4*)&krow[dg + 32];
            #pragma unroll
            for (int j = 0; j < 4; ++j) {
                float freq = exp2f((float)(dg + j) * NEGF);
                float rv   = (float)t_k * freq * INV2PI;
                rv -= floorf(rv);
                float s = __builtin_amdgcn_sinf(rv);
                float c = __builtin_amdgcn_cosf(rv);
                sK[key][dg + j]      = (__bf16)(k0[j] * c - k1[j] * s);
                sK[key][dg + 32 + j] = (__bf16)(k1[j] * c + k0[j] * s);
            }
        }
        // ---- stage V transposed [dim][key] ----
        {
            const int key = tid >> 3;
            const int dg  = (tid & 7) * 8;
            const float* vrow = vbh + (size_t)(kt * KT + key) * HSZ;
            floatx4 v0 = *(const floatx4*)&vrow[dg];
            floatx4 v1 = *(const floatx4*)&vrow[dg + 4];
            #pragma unroll
            for (int j = 0; j < 4; ++j) {
                sV[dg + j][key]     = (__bf16)v0[j];
                sV[dg + 4 + j][key] = (__bf16)v1[j];
            }
        }
        __syncthreads();

        // ---- QK^T: S tile 16x32 (two 16-key n-tiles) ----
        float Sv[2][4];
        #pragma unroll
        for (int nt = 0; nt < 2; ++nt) {
            const int key = nt * 16 + lane15;          // B[k][n]: n = lane15
            bf16x8 bK0 = *(const bf16x8*)&sK[key][quad * 8];
            bf16x8 bK1 = *(const bf16x8*)&sK[key][quad * 8 + 32];
            floatx4 acc = {0.f,0.f,0.f,0.f};
            acc = __builtin_amdgcn_mfma_f32_16x16x32_bf16(aQ0, bK0, acc, 0, 0, 0);
            acc = __builtin_amdgcn_mfma_f32_16x16x32_bf16(aQ1, bK1, acc, 0, 0, 0);
            const float t_k0 = (float)(kt * KT + nt * 16 + lane15);
            #pragma unroll
            for (int r = 0; r < 4; ++r) {
                // scores*scale + alibi slope*(k - q)
                Sv[nt][r] = acc[r] * scale + slope * (t_k0 - (float)(q_glb_base + r));
            }
        }

        // ---- online softmax (row = quad*4 + r, 16 lanes/row) ----
        #pragma unroll
        for (int r = 0; r < 4; ++r) {
            float mx = fmaxf(Sv[0][r], Sv[1][r]);
            mx = fmaxf(mx, __shfl_xor(mx, 1));
            mx = fmaxf(mx, __shfl_xor(mx, 2));
            mx = fmaxf(mx, __shfl_xor(mx, 4));
            mx = fmaxf(mx, __shfl_xor(mx, 8));
            float mnew  = fmaxf(mrow[r], mx);
            float alpha = __expf(mrow[r] - mnew);      // first iter: exp(-inf)=0
            mrow[r] = mnew;
            float p0 = __expf(Sv[0][r] - mnew);
            float p1 = __expf(Sv[1][r] - mnew);
            float ps = p0 + p1;
            ps += __shfl_xor(ps, 1);
            ps += __shfl_xor(ps, 2);
            ps += __shfl_xor(ps, 4);
            ps += __shfl_xor(ps, 8);
            lrow[r] = lrow[r] * alpha + ps;
            O0[r] *= alpha; O1[r] *= alpha; O2[r] *= alpha; O3[r] *= alpha;
            const int row = quad * 4 + r;              // C-layout -> LDS for A-layout reload
            sP[wave][row][lane15]      = (__bf16)p0;
            sP[wave][row][16 + lane15] = (__bf16)p1;
        }

        // ---- PV: O[16 q][64 d] += P(16x32) * V(32x64) ----
        bf16x8 aP  = *(const bf16x8*)&sP[wave][lane15][quad * 8];
        bf16x8 bV0 = *(const bf16x8*)&sV[ 0 + lane15][quad * 8];
        bf16x8 bV1 = *(const bf16x8*)&sV[16 + lane15][quad * 8];
        bf16x8 bV2 = *(const bf16x8*)&sV[32 + lane15][quad * 8];
        bf16x8 bV3 = *(const bf16x8*)&sV[48 + lane15][quad * 8];
        O0 = __builtin_amdgcn_mfma_f32_16x16x32_bf16(aP, bV0, O0, 0, 0, 0);
        O1 = __builtin_amdgcn_mfma_f32_16x16x32_bf16(aP, bV1, O1, 0, 0, 0);
        O2 = __builtin_amdgcn_mfma_f32_16x16x32_bf16(aP, bV2, O2, 0, 0, 0);
        O3 = __builtin_amdgcn_mfma_f32_16x16x32_bf16(aP, bV3, O3, 0, 0, 0);
    }

    // ---- epilogue: normalize and store fp32 ----
    #pragma unroll
    for (int r = 0; r < 4; ++r) {
        const float inv = 1.0f / lrow[r];
        const size_t base = (((size_t)b * TT + (size_t)(q_glb_base + r)) * HSZ)
                          + h * HDIM + lane15;
        Out[base +  0] = O0[r] * inv;
        Out[base + 16] = O1[r] * inv;
        Out[base + 32] = O2[r] * inv;
        Out[base + 48] = O3[r] * inv;
    }
}

extern "C" void kernel_launch(void* const* d_in, const int* in_sizes, int n_in,
                              void* d_out, int out_size, void* d_ws, size_t ws_size,
                              hipStream_t stream) {
    const float* q = (const float*)d_in[0];
    const float* k = (const float*)d_in[1];
    const float* v = (const float*)d_in[2];
    float* out = (float*)d_out;
    dim3 grid(TB * NHEADS * (TT / QB));   // 1024 blocks
    attn_rope_alibi_kernel<<<grid, 256, 0, stream>>>(q, k, v, out);
}